// Round 13
// baseline (1233.776 us; speedup 1.0000x reference)
//
#include <hip/hip_runtime.h>

// ---------------------------------------------------------------------------
// Graphormer forward, MI355X. Round 12: fattn LDS diet -> 3 blocks/CU.
//  - fattn_k: 512 thr (8 waves), QROWS=128, SPLIT=8 (KSP=256, NT=8),
//    SINGLE-buffered Ks/Vs/Bls (50.2 KB LDS): stage(t+1) issued only after
//    the post-PV barrier (all reads of the single buffers provably done).
//    vmcnt(0) at tile top. Occupancy 40% -> ~75% (3 blocks/CU); co-resident
//    blocks hide the un-double-buffered staging latency.
//  - combine_k: 8 partials. Everything else identical to round 11 (741 us).
// ---------------------------------------------------------------------------

constexpr int NN    = 2048;   // nodes
constexpr int EE    = 32768;  // edges
constexpr int IN_ND = 128;
constexpr int ND    = 256;
constexpr int IN_ED = 64;
constexpr int ED    = 128;
constexpr int H     = 8;
constexpr int FF    = 1024;
constexpr int NL    = 3;
constexpr int LMAX  = 5;
constexpr int MAXDEG= 64;
constexpr int SPLIT = 8;
constexpr int KSP   = NN / SPLIT;   // keys per split = 256
constexpr int QROWS = 128;          // q-rows per block

enum { E_NONE = 0, E_BIAS = 1, E_BIAS_RES = 2, E_BIAS_GELU = 3 };

using u16 = unsigned short;
using short8 = __attribute__((ext_vector_type(8))) short;   // 8 bf16 (4 VGPR)
using f32x4  = __attribute__((ext_vector_type(4))) float;
using u32x4  = __attribute__((ext_vector_type(4))) unsigned int;

__device__ __forceinline__ u16 f2bf(float f) {              // RNE f32->bf16
    unsigned u = __float_as_uint(f);
    u += 0x7fff + ((u >> 16) & 1);
    return (u16)(u >> 16);
}
__device__ __forceinline__ float bf2f(u16 h) {
    return __uint_as_float((unsigned)h << 16);
}
__device__ __forceinline__ float gelu_f(float x) {
    return 0.5f * x * (1.0f + erff(x * 0.70710678118654752440f));
}

#define GLL16(gsrc, ldst)                                                     \
    __builtin_amdgcn_global_load_lds(                                         \
        (const __attribute__((address_space(1))) void*)(gsrc),                \
        (__attribute__((address_space(3))) void*)(ldst), 16, 0, 0)

// ---------------------------------------------------------------------------
// bf16 MFMA GEMM, 128x128 tile, BK=32. Used ONLY for fused QKV (grid z=3):
// per-z bias pointer, z-strided A/B/C.
// ---------------------------------------------------------------------------
template<int EPI, int OBF>
__global__ __launch_bounds__(256)
void mgemm_k(const u16* __restrict__ A, int lda, long aZs,
             const u16* __restrict__ B, int ldb, long bZs,
             void* __restrict__ Cp, int ldc, long cZs,
             int K, const float* __restrict__ bias0,
             const float* __restrict__ bias1, const float* __restrict__ bias2)
{
    const int z = blockIdx.z;
    A += (long)z * aZs;
    B += (long)z * bZs;
    const float* bias = (z == 0) ? bias0 : (z == 1 ? bias1 : bias2);
    const int row0 = blockIdx.y * 128, col0 = blockIdx.x * 128;
    const int tid = threadIdx.x;
    const int lane = tid & 63, wv = tid >> 6;
    const int wr = wv >> 1, wc = wv & 1;
    const int fl = lane & 15, kg = lane >> 4;

    __shared__ u16 As[128 * 32];
    __shared__ u16 Bs[128 * 32];

    int aoff[4], boff[4];
#pragma unroll
    for (int m = 0; m < 4; m++) {
        int r = wr * 64 + m * 16 + fl;
        aoff[m] = r * 64 + ((kg ^ ((r >> 1) & 3)) * 16);
        r = wc * 64 + m * 16 + fl;
        boff[m] = r * 64 + ((kg ^ ((r >> 1) & 3)) * 16);
    }

    const int id0 = tid * 2, id1 = id0 + 1;
    const int sr0 = id0 >> 2, sl0 = id0 & 3;
    const int sr1 = id1 >> 2, sl1 = id1 & 3;
    const int wb0 = sr0 * 64 + ((sl0 ^ ((sr0 >> 1) & 3)) * 16);
    const int wb1 = sr1 * 64 + ((sl1 ^ ((sr1 >> 1) & 3)) * 16);
    const u16* ga0 = A + (long)(row0 + sr0) * lda + sl0 * 8;
    const u16* ga1 = A + (long)(row0 + sr1) * lda + sl1 * 8;
    const u16* gb0 = B + (long)(col0 + sr0) * ldb + sl0 * 8;
    const u16* gb1 = B + (long)(col0 + sr1) * ldb + sl1 * 8;

    const f32x4 zero = {0.f, 0.f, 0.f, 0.f};
    f32x4 acc[4][4];
#pragma unroll
    for (int m = 0; m < 4; m++)
#pragma unroll
        for (int n = 0; n < 4; n++) acc[m][n] = zero;

    for (int k0 = 0; k0 < K; k0 += 32) {
        const uint4 va0 = *(const uint4*)(ga0 + k0);
        const uint4 va1 = *(const uint4*)(ga1 + k0);
        const uint4 vb0 = *(const uint4*)(gb0 + k0);
        const uint4 vb1 = *(const uint4*)(gb1 + k0);
        __syncthreads();
        *(uint4*)((char*)As + wb0) = va0;
        *(uint4*)((char*)As + wb1) = va1;
        *(uint4*)((char*)Bs + wb0) = vb0;
        *(uint4*)((char*)Bs + wb1) = vb1;
        __syncthreads();
        short8 af[4], bfr[4];
#pragma unroll
        for (int m = 0; m < 4; m++)
            af[m] = *(const short8*)((const char*)As + aoff[m]);
#pragma unroll
        for (int n = 0; n < 4; n++)
            bfr[n] = *(const short8*)((const char*)Bs + boff[n]);
#pragma unroll
        for (int m = 0; m < 4; m++)
#pragma unroll
            for (int n = 0; n < 4; n++)
                acc[m][n] = __builtin_amdgcn_mfma_f32_16x16x32_bf16(
                    af[m], bfr[n], acc[m][n], 0, 0, 0);
    }

    float* Cf = (float*)Cp + (long)z * cZs;
    u16*   Cb = (u16*)Cp   + (long)z * cZs;
#pragma unroll
    for (int n = 0; n < 4; n++) {
        const int col = col0 + wc * 64 + n * 16 + fl;
        float bcol = 0.f;
        if constexpr (EPI == E_BIAS || EPI == E_BIAS_RES || EPI == E_BIAS_GELU)
            bcol = bias[col];
#pragma unroll
        for (int m = 0; m < 4; m++) {
            const f32x4 v = acc[m][n];
#pragma unroll
            for (int r = 0; r < 4; r++) {
                const int row = row0 + wr * 64 + m * 16 + kg * 4 + r;
                float x = v[r];
                if constexpr (EPI == E_BIAS)       x += bcol;
                else if constexpr (EPI == E_BIAS_RES)  x += bcol + Cf[(long)row * ldc + col];
                else if constexpr (EPI == E_BIAS_GELU) x = gelu_f(x + bcol);
                if constexpr (OBF) Cb[(long)row * ldc + col] = f2bf(x);
                else               Cf[(long)row * ldc + col] = x;
            }
        }
    }
}

// ---------------------------------------------------------------------------
// bf16 MFMA GEMM, 64x64 tile, BK=64.
// ---------------------------------------------------------------------------
template<int EPI, int OBF>
__global__ __launch_bounds__(256)
void mgemm64_k(const u16* __restrict__ A, int lda,
               const u16* __restrict__ B, int ldb,
               void* __restrict__ Cp, int ldc,
               int K, const float* __restrict__ bias)
{
    const int row0 = blockIdx.y * 64, col0 = blockIdx.x * 64;
    const int tid = threadIdx.x, lane = tid & 63, w = tid >> 6;
    const int wr = w >> 1, wc = w & 1;
    const int fl = lane & 15, kg = lane >> 4;

    __shared__ u16 As[64 * 64];
    __shared__ u16 Bs[64 * 64];

    int aoff[2][2], boff[2][2];
#pragma unroll
    for (int m = 0; m < 2; m++)
#pragma unroll
        for (int ks = 0; ks < 2; ks++) {
            int r = wr * 32 + m * 16 + fl;
            aoff[m][ks] = r * 64 + (((ks * 4 + kg) ^ (r & 7)) * 8);
            r = wc * 32 + m * 16 + fl;
            boff[m][ks] = r * 64 + (((ks * 4 + kg) ^ (r & 7)) * 8);
        }
    const int i0 = tid, i1 = tid + 256;
    const int ar0 = i0 >> 3, as0 = i0 & 7, ar1 = i1 >> 3, as1 = i1 & 7;
    const u16* gA0 = A + (long)(row0 + ar0) * lda + ((as0 ^ (ar0 & 7)) * 8);
    const u16* gA1 = A + (long)(row0 + ar1) * lda + ((as1 ^ (ar1 & 7)) * 8);
    const u16* gB0 = B + (long)(col0 + ar0) * ldb + ((as0 ^ (ar0 & 7)) * 8);
    const u16* gB1 = B + (long)(col0 + ar1) * ldb + ((as1 ^ (ar1 & 7)) * 8);

    const f32x4 zero = {0.f, 0.f, 0.f, 0.f};
    f32x4 acc[2][2];
#pragma unroll
    for (int m = 0; m < 2; m++)
#pragma unroll
        for (int n = 0; n < 2; n++) acc[m][n] = zero;

    for (int k0 = 0; k0 < K; k0 += 64) {
        const uint4 a0 = *(const uint4*)(gA0 + k0);
        const uint4 a1 = *(const uint4*)(gA1 + k0);
        const uint4 b0 = *(const uint4*)(gB0 + k0);
        const uint4 b1 = *(const uint4*)(gB1 + k0);
        __syncthreads();
        *(uint4*)((char*)As + i0 * 16) = a0;
        *(uint4*)((char*)As + i1 * 16) = a1;
        *(uint4*)((char*)Bs + i0 * 16) = b0;
        *(uint4*)((char*)Bs + i1 * 16) = b1;
        __syncthreads();
        short8 af[2][2], bf_[2][2];
#pragma unroll
        for (int m = 0; m < 2; m++)
#pragma unroll
            for (int ks = 0; ks < 2; ks++) {
                af[m][ks]  = *(const short8*)(As + aoff[m][ks]);
                bf_[m][ks] = *(const short8*)(Bs + boff[m][ks]);
            }
#pragma unroll
        for (int m = 0; m < 2; m++)
#pragma unroll
            for (int n = 0; n < 2; n++)
#pragma unroll
                for (int ks = 0; ks < 2; ks++)
                    acc[m][n] = __builtin_amdgcn_mfma_f32_16x16x32_bf16(
                        af[m][ks], bf_[n][ks], acc[m][n], 0, 0, 0);
    }

    float* Cf = (float*)Cp;
    u16*   Cb = (u16*)Cp;
#pragma unroll
    for (int n = 0; n < 2; n++) {
        const int col = col0 + wc * 32 + n * 16 + fl;
        float bcol = 0.f;
        if constexpr (EPI == E_BIAS || EPI == E_BIAS_RES || EPI == E_BIAS_GELU)
            bcol = bias[col];
#pragma unroll
        for (int m = 0; m < 2; m++) {
            const f32x4 v = acc[m][n];
#pragma unroll
            for (int r = 0; r < 4; r++) {
                const int row = row0 + wr * 32 + m * 16 + kg * 4 + r;
                float x = v[r];
                if constexpr (EPI == E_BIAS)       x += bcol;
                else if constexpr (EPI == E_BIAS_RES)  x += bcol + Cf[(long)row * ldc + col];
                else if constexpr (EPI == E_BIAS_GELU) x = gelu_f(x + bcol);
                if constexpr (OBF) Cb[(long)row * ldc + col] = f2bf(x);
                else               Cf[(long)row * ldc + col] = x;
            }
        }
    }
}

// ---------------------------------------------------------------------------
// Split-K flash attention, 512 thr = 8 waves, QROWS=128, SPLIT=8 (NT=8),
// SINGLE-buffered Ks/Vs/Bls (50 KB LDS -> 3 blocks/CU).
// Per tile: [vmcnt(0); barrier] -> QK^T -> P=exp(s+bias) -> Ps -> PV ->
// [lgkmcnt(0); barrier] -> stage(t+1)+bias(t+1) (post-barrier: all reads of
// the single buffers are done, overwrite safe). Co-resident blocks hide the
// staging latency. Shuffle-free softmax (m==0, ones-MFMA row-sums).
// ---------------------------------------------------------------------------
__global__ __launch_bounds__(512, 4)
void fattn_k(const u16* __restrict__ qb, const u16* __restrict__ kb,
             const u16* __restrict__ vT, u16* __restrict__ sc,
             float* __restrict__ ml)
{
    const int hh = blockIdx.x;
    const int row0 = blockIdx.y * QROWS;
    const int sp = blockIdx.z;
    const int kbase = sp * KSP;
    constexpr int NT = KSP / 32;       // 8 tiles
    const int tid = threadIdx.x, lane = tid & 63, w = tid >> 6;   // w 0..7
    const int fl = lane & 15, kg = lane >> 4;
    const long NN2 = (long)NN * NN;

    __shared__ u16 Ks[32 * 256];       // 16 KB [keyrow][256k] swz
    __shared__ u16 Vs[256 * 32];       // 16 KB [d][32keys] swz
    __shared__ u16 Bls[QROWS * 32];    //  8 KB bias [row][32cols]
    __shared__ u16 Ps[8 * 16 * 40];    // 10 KB per-wave P tile, pitch 40

    auto stage = [&](int t) {
        const int kt0 = kbase + t * 32;
#pragma unroll
        for (int c = 0; c < 2; c++) {
            const int idx = c * 512 + tid;
            const int kr = idx >> 5, ksl = idx & 31;
            GLL16(kb + (long)(kt0 + kr) * (H * ND) + hh * ND + ((ksl ^ (kr & 7)) * 8),
                  Ks + idx * 8);
            const int vr = idx >> 2, vsl = idx & 3;
            GLL16(vT + (long)(hh * ND + vr) * NN + kt0 + ((vsl ^ ((vr >> 1) & 3)) * 8),
                  Vs + idx * 8);
        }
    };
    // bias: thread tid loads row (row0 + tid>>2), 8 cols (tid&3)*8 -> 64B per
    // 4 threads; 512 threads cover 128 rows x 32 cols.
    auto stage_bias = [&](int t) {
        const u16* g = sc + (long)hh * NN2 + (long)(row0 + (tid >> 2)) * NN
                     + kbase + t * 32 + (tid & 3) * 8;
        GLL16(g, Bls + tid * 8);
    };

    // Q fragments: wave w owns rows row0 + w*16 .. +16
    short8 qf[8];
    {
        const u16* qrow = qb + (long)(row0 + w * 16 + fl) * (H * ND) + hh * ND;
#pragma unroll
        for (int ks = 0; ks < 8; ks++)
            qf[ks] = *(const short8*)(qrow + ks * 32 + kg * 8);
    }
    stage(0);
    stage_bias(0);

    short8 ones;                        // bf16 1.0 x8 (0x3F80)
#pragma unroll
    for (int i = 0; i < 8; i++) ones[i] = (short)0x3F80;

    f32x4 O[16];
#pragma unroll
    for (int of = 0; of < 16; of++) O[of] = f32x4{0.f, 0.f, 0.f, 0.f};
    f32x4 lac = {0.f, 0.f, 0.f, 0.f};   // row-sums via ones-MFMA

    const float scale = 1.f / 16.f;
    for (int t = 0; t < NT; t++) {
        asm volatile("s_waitcnt vmcnt(0)" ::: "memory");   // own stage landed
        __builtin_amdgcn_sched_barrier(0);
        asm volatile("s_barrier" ::: "memory");            // all waves' stage landed
        __builtin_amdgcn_sched_barrier(0);

        // S = Q K^T from Ks
        f32x4 s[2] = {f32x4{0.f,0.f,0.f,0.f}, f32x4{0.f,0.f,0.f,0.f}};
        __builtin_amdgcn_s_setprio(1);
#pragma unroll
        for (int ks = 0; ks < 8; ks++)
#pragma unroll
            for (int cf = 0; cf < 2; cf++) {
                const int mlr = cf * 16 + fl;
                const short8 kf = *(const short8*)(Ks + mlr * 256
                                                   + (((ks * 4 + kg) ^ (mlr & 7)) * 8));
                s[cf] = __builtin_amdgcn_mfma_f32_16x16x32_bf16(qf[ks], kf, s[cf], 0, 0, 0);
            }
        __builtin_amdgcn_s_setprio(0);

        // P = exp(s*scale + bias), bias fragment from LDS
        const u16* bl = Bls + (w * 16 + kg * 4) * 32;
        float p[2][4];
#pragma unroll
        for (int cf = 0; cf < 2; cf++)
#pragma unroll
            for (int r = 0; r < 4; r++)
                p[cf][r] = __expf(s[cf][r] * scale
                                  + bf2f(bl[r * 32 + cf * 16 + fl]));
        // P -> per-wave LDS bounce
#pragma unroll
        for (int cf = 0; cf < 2; cf++)
#pragma unroll
            for (int r = 0; r < 4; r++)
                Ps[w * 640 + (kg * 4 + r) * 40 + cf * 16 + fl] = f2bf(p[cf][r]);

        // PV: O += P * V; l += P * 1 (ones-MFMA)
        const short8 pa = *(const short8*)(Ps + w * 640 + fl * 40 + kg * 8);
        __builtin_amdgcn_s_setprio(1);
        lac = __builtin_amdgcn_mfma_f32_16x16x32_bf16(pa, ones, lac, 0, 0, 0);
#pragma unroll
        for (int of = 0; of < 16; of++) {
            const int d = of * 16 + fl;
            const short8 vf = *(const short8*)(Vs + d * 32
                                               + ((kg ^ ((d >> 1) & 3)) * 8));
            O[of] = __builtin_amdgcn_mfma_f32_16x16x32_bf16(pa, vf, O[of], 0, 0, 0);
        }
        __builtin_amdgcn_s_setprio(0);

        asm volatile("s_waitcnt lgkmcnt(0)" ::: "memory"); // own LDS reads done
        __builtin_amdgcn_sched_barrier(0);
        asm volatile("s_barrier" ::: "memory");            // all reads done
        __builtin_amdgcn_sched_barrier(0);
        if (t + 1 < NT) {                                  // overwrite safe now
            stage(t + 1);
            stage_bias(t + 1);
        }
    }

    // ---- epilogue: UNNORMALIZED O -> sc cols [sp*256, sp*256+256), l -> ml
    u16* op = sc + (long)hh * NN2 + sp * KSP;
#pragma unroll
    for (int of = 0; of < 16; of++)
#pragma unroll
        for (int r = 0; r < 4; r++) {
            const int row = row0 + w * 16 + kg * 4 + r;
            op[(long)row * NN + of * 16 + fl] = f2bf(O[of][r]);
        }
    if (fl == 0) {
#pragma unroll
        for (int r = 0; r < 4; r++) {
            const int row = row0 + w * 16 + kg * 4 + r;
            ml[((long)sp * H + hh) * NN + row] = lac[r];
        }
    }
}

// ---------------------------------------------------------------------------
// Combine split partials: o2[n][h*256+d] = sum_z O_z / sum_z l_z (unweighted).
// One thread per (h,n,8d). d8 in [0,32) covers 256 d.
// ---------------------------------------------------------------------------
__global__ __launch_bounds__(256)
void combine_k(const u16* __restrict__ sc, const float* __restrict__ ml,
               u16* __restrict__ o2)
{
    const int idx = blockIdx.x * 256 + threadIdx.x;
    const int d8 = idx & 31;
    const int n  = (idx >> 5) & (NN - 1);
    const int h  = idx >> 16;
    const long NN2 = (long)NN * NN;
    float L = 0.f;
#pragma unroll
    for (int z = 0; z < SPLIT; z++)
        L += ml[((long)z * H + h) * NN + n];
    const float invL = 1.f / L;
    float acc[8] = {0.f,0.f,0.f,0.f,0.f,0.f,0.f,0.f};
#pragma unroll
    for (int z = 0; z < SPLIT; z++) {
        const u32x4 q = *(const u32x4*)(sc + (long)h * NN2 + (long)n * NN
                                        + z * KSP + d8 * 8);
        acc[0] += bf2f(q.x & 0xffff); acc[1] += bf2f(q.x >> 16);
        acc[2] += bf2f(q.y & 0xffff); acc[3] += bf2f(q.y >> 16);
        acc[4] += bf2f(q.z & 0xffff); acc[5] += bf2f(q.z >> 16);
        acc[6] += bf2f(q.w & 0xffff); acc[7] += bf2f(q.w >> 16);
    }
    uint4 o;
    o.x = (unsigned)f2bf(acc[0] * invL) | ((unsigned)f2bf(acc[1] * invL) << 16);
    o.y = (unsigned)f2bf(acc[2] * invL) | ((unsigned)f2bf(acc[3] * invL) << 16);
    o.z = (unsigned)f2bf(acc[4] * invL) | ((unsigned)f2bf(acc[5] * invL) << 16);
    o.w = (unsigned)f2bf(acc[6] * invL) | ((unsigned)f2bf(acc[7] * invL) << 16);
    *(uint4*)(o2 + (long)n * (H * ND) + h * ND + d8 * 8) = o;
}

// ---------------------------------------------------------------------------
// Tiled transpose + (optional) f32->bf16 convert.
// ---------------------------------------------------------------------------
template<int INF32>
__global__ __launch_bounds__(256)
void transp_k(const void* __restrict__ inp, long inZs,
              u16* __restrict__ out, long outZs, int R, int C)
{
    const int z = blockIdx.z;
    const int r0 = blockIdx.y * 64, c0 = blockIdx.x * 64;
    __shared__ u16 t[64][68];
    const int tx = threadIdx.x & 63, ty = threadIdx.x >> 6;
    if constexpr (INF32) {
        const float* in = (const float*)inp + (long)z * inZs;
#pragma unroll
        for (int i = 0; i < 16; i++) {
            const int r = i * 4 + ty;
            t[r][tx] = f2bf(in[(long)(r0 + r) * C + c0 + tx]);
        }
    } else {
        const u16* in = (const u16*)inp + (long)z * inZs;
#pragma unroll
        for (int i = 0; i < 16; i++) {
            const int r = i * 4 + ty;
            t[r][tx] = in[(long)(r0 + r) * C + c0 + tx];
        }
    }
    __syncthreads();
    u16* o = out + (long)z * outZs;
#pragma unroll
    for (int i = 0; i < 16; i++) {
        const int r = i * 4 + ty;
        o[(long)(c0 + r) * R + r0 + tx] = t[tx][r];
    }
}

// elementwise f32 -> bf16
__global__ __launch_bounds__(256)
void cvt_k(const float* __restrict__ in, u16* __restrict__ out)
{
    const long i = (long)blockIdx.x * 256 + threadIdx.x;
    const float4 v = ((const float4*)in)[i];
    ushort4 o;
    o.x = f2bf(v.x); o.y = f2bf(v.y); o.z = f2bf(v.z); o.w = f2bf(v.w);
    ((ushort4*)out)[i] = o;
}

// ---------------------------------------------------------------------------
// LayerNorm rows of ND=256, f32 in -> bf16 out.
// ---------------------------------------------------------------------------
__global__ __launch_bounds__(256)
void ln_k(const float* __restrict__ x, const float* __restrict__ w,
          const float* __restrict__ b, u16* __restrict__ y)
{
    const int wid = threadIdx.x >> 6, lane = threadIdx.x & 63;
    const int row = blockIdx.x * 4 + wid;
    const float4 v = reinterpret_cast<const float4*>(x + (long)row * ND)[lane];
    float s = v.x + v.y + v.z + v.w;
#pragma unroll
    for (int o = 32; o >= 1; o >>= 1) s += __shfl_xor(s, o);
    const float mean = s * (1.f / ND);
    const float d0 = v.x - mean, d1 = v.y - mean, d2 = v.z - mean, d3 = v.w - mean;
    float sq = d0 * d0 + d1 * d1 + d2 * d2 + d3 * d3;
#pragma unroll
    for (int o = 32; o >= 1; o >>= 1) sq += __shfl_xor(sq, o);
    const float rstd = rsqrtf(sq * (1.f / ND) + 1e-5f);
    const float4 wv = reinterpret_cast<const float4*>(w)[lane];
    const float4 bv = reinterpret_cast<const float4*>(b)[lane];
    ushort4 o4;
    o4.x = f2bf(d0 * rstd * wv.x + bv.x);
    o4.y = f2bf(d1 * rstd * wv.y + bv.y);
    o4.z = f2bf(d2 * rstd * wv.z + bv.z);
    o4.w = f2bf(d3 * rstd * wv.w + bv.w);
    reinterpret_cast<ushort4*>(y + (long)row * ND)[lane] = o4;
}

// ---------------------------------------------------------------------------
// Edge-dot precompute, bf16 out: dtb[s][e][h]. grid (EE/256, LMAX)
// ---------------------------------------------------------------------------
__global__ __launch_bounds__(256)
void dotsT_k(const u16* __restrict__ e, const float* __restrict__ evl,
             u16* __restrict__ dtb)
{
    const int s = blockIdx.y;
    const int ei = blockIdx.x * 256 + threadIdx.x;
    __shared__ float evs[H * ED];
    for (int i = threadIdx.x; i < H * ED; i += 256)
        evs[i] = evl[((i >> 7) * LMAX + s) * ED + (i & 127)];
    __syncthreads();
    const uint4* er = (const uint4*)(e + (long)ei * ED);
    float c[H];
#pragma unroll
    for (int h = 0; h < H; h++) c[h] = 0.f;
#pragma unroll
    for (int d8 = 0; d8 < ED / 8; d8++) {
        const uint4 q = er[d8];
        float f[8];
        f[0] = bf2f(q.x & 0xffff); f[1] = bf2f(q.x >> 16);
        f[2] = bf2f(q.y & 0xffff); f[3] = bf2f(q.y >> 16);
        f[4] = bf2f(q.z & 0xffff); f[5] = bf2f(q.z >> 16);
        f[6] = bf2f(q.w & 0xffff); f[7] = bf2f(q.w >> 16);
#pragma unroll
        for (int h = 0; h < H; h++) {
            const float* w = &evs[h * ED + d8 * 8];
            c[h] += w[0] * f[0] + w[1] * f[1] + w[2] * f[2] + w[3] * f[3]
                  + w[4] * f[4] + w[5] * f[5] + w[6] * f[6] + w[7] * f[7];
        }
    }
    uint4 o;
    o.x = (unsigned)f2bf(c[0]) | ((unsigned)f2bf(c[1]) << 16);
    o.y = (unsigned)f2bf(c[2]) | ((unsigned)f2bf(c[3]) << 16);
    o.z = (unsigned)f2bf(c[4]) | ((unsigned)f2bf(c[5]) << 16);
    o.w = (unsigned)f2bf(c[6]) | ((unsigned)f2bf(c[7]) << 16);
    *(uint4*)(dtb + ((long)s * EE + ei) * H) = o;
}

// ---------------------------------------------------------------------------
// Path compaction.
// ---------------------------------------------------------------------------
__global__ __launch_bounds__(256)
void pack_k(const int* __restrict__ ndist, const int* __restrict__ epaths,
            unsigned* __restrict__ pc0, unsigned* __restrict__ pc1,
            unsigned* __restrict__ pc2)
{
    const long idx = (long)blockIdx.x * 256 + threadIdx.x;
    const unsigned d = (unsigned)ndist[idx];
    const int* ep = epaths + idx * LMAX;
    const unsigned e0 = ep[0], e1 = ep[1], e2 = ep[2], e3 = ep[3], e4 = ep[4];
    pc0[idx] = d | (e0 << 8);
    pc1[idx] = e1 | (e2 << 16);
    pc2[idx] = e3 | (e4 << 16);
}

// ---------------------------------------------------------------------------
// Attention bias -> bf16 scores init.
// ---------------------------------------------------------------------------
__global__ __launch_bounds__(256)
void bias_k(const unsigned* __restrict__ pc0, const unsigned* __restrict__ pc1,
            const unsigned* __restrict__ pc2, const float* __restrict__ bspat,
            const u16* __restrict__ dtb, u16* __restrict__ sc)
{
    const long idx = (long)blockIdx.x * 256 + threadIdx.x;
    const unsigned w0 = pc0[idx], w1 = pc1[idx], w2 = pc2[idx];
    const int d = (int)(w0 & 255u);
    float bb = 0.f;
    if (d > 0) bb = bspat[(d < LMAX ? d : LMAX) - 1];
    int npe = d - 1;
    npe = npe < 0 ? 0 : (npe > LMAX ? LMAX : npe);
    const int ep[LMAX] = { (int)(w0 >> 8), (int)(w1 & 0xffffu), (int)(w1 >> 16),
                           (int)(w2 & 0xffffu), (int)(w2 >> 16) };
    float c[H];
#pragma unroll
    for (int h = 0; h < H; h++) c[h] = 0.f;
#pragma unroll
    for (int s = 0; s < LMAX; s++) {
        if (s < npe) {
            const uint4 q = *(const uint4*)(dtb + ((long)s * EE + ep[s]) * H);
            c[0] += bf2f(q.x & 0xffff); c[1] += bf2f(q.x >> 16);
            c[2] += bf2f(q.y & 0xffff); c[3] += bf2f(q.y >> 16);
            c[4] += bf2f(q.z & 0xffff); c[5] += bf2f(q.z >> 16);
            c[6] += bf2f(q.w & 0xffff); c[7] += bf2f(q.w >> 16);
        }
    }
    const float inv = npe > 0 ? 1.f / (float)npe : 0.f;
    const long NN2 = (long)NN * NN;
#pragma unroll
    for (int h = 0; h < H; h++)
        sc[(long)h * NN2 + idx] = f2bf(bb + c[h] * inv);
}

__global__ void deg_k(const int* __restrict__ ei, int* __restrict__ ind,
                      int* __restrict__ outd)
{
    const int e = blockIdx.x * 256 + threadIdx.x;
    atomicAdd(&outd[ei[e]], 1);
    atomicAdd(&ind[ei[EE + e]], 1);
}

__global__ void degembed_k(float* __restrict__ h, const int* __restrict__ ind,
                           const int* __restrict__ outd,
                           const float* __restrict__ z_in,
                           const float* __restrict__ z_out)
{
    const int idx = blockIdx.x * 256 + threadIdx.x;
    const int n = idx >> 8, c = idx & 255;
    int di = ind[n];  di = di > (MAXDEG - 1) ? (MAXDEG - 1) : di;
    int dw = outd[n]; dw = dw > (MAXDEG - 1) ? (MAXDEG - 1) : dw;
    h[idx] += z_in[di * ND + c] + z_out[dw * ND + c];
}

__global__ void sentinel_k(float* o) { o[0] = 12345.0f; }

// ---------------------------------------------------------------------------
extern "C" void kernel_launch(void* const* d_in, const int* in_sizes, int n_in,
                              void* d_out, int out_size, void* d_ws, size_t ws_size,
                              hipStream_t stream)
{
    const float* x      = (const float*)d_in[0];
    const int*   eidx   = (const int*)d_in[1];
    const float* eattr  = (const float*)d_in[2];
    const int*   ndist  = (const int*)d_in[3];
    const int*   epaths = (const int*)d_in[4];
    const float* Wn_in  = (const float*)d_in[5];
    const float* bn_in  = (const float*)d_in[6];
    const float* We_in  = (const float*)d_in[7];
    const float* be_in  = (const float*)d_in[8];
    const float* z_in   = (const float*)d_in[9];
    const float* z_out  = (const float*)d_in[10];
    const float* bspat  = (const float*)d_in[11];
    const float* ln1w   = (const float*)d_in[12];
    const float* ln1b   = (const float*)d_in[13];
    const float* ln2w   = (const float*)d_in[14];
    const float* ln2b   = (const float*)d_in[15];
    const float* Wq     = (const float*)d_in[16];
    const float* bq     = (const float*)d_in[17];
    const float* Wk     = (const float*)d_in[18];
    const float* bk     = (const float*)d_in[19];
    const float* Wv     = (const float*)d_in[20];
    const float* bv     = (const float*)d_in[21];
    const float* evec   = (const float*)d_in[22];
    const float* Wo     = (const float*)d_in[23];
    const float* bo     = (const float*)d_in[24];
    const float* Wff1   = (const float*)d_in[25];
    const float* bff1   = (const float*)d_in[26];
    const float* Wff2   = (const float*)d_in[27];
    const float* bff2   = (const float*)d_in[28];
    const float* Wout   = (const float*)d_in[29];
    const float* bout   = (const float*)d_in[30];
    float* out = (float*)d_out;

    // ---- workspace carve-up ----
    char* p = (char*)d_ws;
    auto alloc = [&](size_t bytes) -> char* {
        char* r = p;
        p += (bytes + 255) & ~(size_t)255;
        return r;
    };
    float* h    = (float*)alloc((size_t)NN * ND * 4);
    u16*   hb   = (u16*)alloc((size_t)NN * ND * 2);
    u16*   xb   = (u16*)alloc((size_t)NN * IN_ND * 2);
    u16*   xnb  = (u16*)alloc((size_t)NN * ND * 2);
    u16*   eb   = (u16*)alloc((size_t)EE * IN_ED * 2);
    u16*   e_bf = (u16*)alloc((size_t)EE * ED * 2);
    u16*   qb   = (u16*)alloc((size_t)NN * H * ND * 2);   // qb,kb,vb contiguous
    u16*   kb   = (u16*)alloc((size_t)NN * H * ND * 2);
    u16*   vb   = (u16*)alloc((size_t)NN * H * ND * 2);
    u16*   vT   = (u16*)alloc((size_t)NN * H * ND * 2);
    u16*   o2   = (u16*)alloc((size_t)NN * H * ND * 2);
    u16*   ff1b = (u16*)alloc((size_t)NN * FF * 2);
    u16*   dtb  = (u16*)alloc((size_t)LMAX * EE * H * 2);
    u16*   WqT  = (u16*)alloc((size_t)NL * H * ND * ND * 2);  // WqT,WkT,WvT contiguous
    u16*   WkT  = (u16*)alloc((size_t)NL * H * ND * ND * 2);
    u16*   WvT  = (u16*)alloc((size_t)NL * H * ND * ND * 2);
    u16*   WoT  = (u16*)alloc((size_t)NL * ND * H * ND * 2);
    u16*   W1T  = (u16*)alloc((size_t)NL * FF * ND * 2);
    u16*   W2T  = (u16*)alloc((size_t)NL * ND * FF * 2);
    u16*   WnT  = (u16*)alloc((size_t)ND * IN_ND * 2);
    u16*   WeT  = (u16*)alloc((size_t)ED * IN_ED * 2);
    u16*   WouT = (u16*)alloc((size_t)ND * ND * 2);
    int*   ind  = (int*)alloc(NN * 4);
    int*   outd = (int*)alloc(NN * 4);
    unsigned* pc0 = (unsigned*)alloc((size_t)NN * NN * 4);
    unsigned* pc1 = (unsigned*)alloc((size_t)NN * NN * 4);
    unsigned* pc2 = (unsigned*)alloc((size_t)NN * NN * 4);
    float* ml   = (float*)alloc((size_t)SPLIT * H * NN * 4);
    u16*   sc   = (u16*)alloc((size_t)H * NN * NN * 2);
    if ((size_t)(p - (char*)d_ws) > ws_size) {
        sentinel_k<<<1, 1, 0, stream>>>(out);
        return;
    }

    const long NN2 = (long)NN * NN;

    // ---- degrees + path compaction ----
    hipMemsetAsync(ind, 0, NN * 4, stream);
    hipMemsetAsync(outd, 0, NN * 4, stream);
    deg_k<<<EE / 256, 256, 0, stream>>>(eidx, ind, outd);
    pack_k<<<(int)(NN2 / 256), 256, 0, stream>>>(ndist, epaths, pc0, pc1, pc2);

    // ---- input converts + weight transposes ----
    cvt_k<<<NN * IN_ND / 1024, 256, 0, stream>>>(x, xb);
    cvt_k<<<EE * IN_ED / 1024, 256, 0, stream>>>(eattr, eb);
    transp_k<1><<<dim3(4, 4, NL * H), 256, 0, stream>>>(Wq, ND * ND, WqT, ND * ND, ND, ND);
    transp_k<1><<<dim3(4, 4, NL * H), 256, 0, stream>>>(Wk, ND * ND, WkT, ND * ND, ND, ND);
    transp_k<1><<<dim3(4, 4, NL * H), 256, 0, stream>>>(Wv, ND * ND, WvT, ND * ND, ND, ND);
    transp_k<1><<<dim3(4, 32, NL), 256, 0, stream>>>(Wo, (long)H * ND * ND, WoT, (long)H * ND * ND, H * ND, ND);
    transp_k<1><<<dim3(16, 4, NL), 256, 0, stream>>>(Wff1, (long)ND * FF, W1T, (long)ND * FF, ND, FF);
    transp_k<1><<<dim3(4, 16, NL), 256, 0, stream>>>(Wff2, (long)ND * FF, W2T, (long)ND * FF, FF, ND);
    transp_k<1><<<dim3(4, 2, 1), 256, 0, stream>>>(Wn_in, 0, WnT, 0, IN_ND, ND);
    transp_k<1><<<dim3(2, 1, 1), 256, 0, stream>>>(We_in, 0, WeT, 0, IN_ED, ED);
    transp_k<1><<<dim3(4, 4, 1), 256, 0, stream>>>(Wout, 0, WouT, 0, ND, ND);

    // ---- input projections ----
    mgemm64_k<E_BIAS, 0><<<dim3(4, 32), 256, 0, stream>>>(
        xb, IN_ND, WnT, IN_ND, h, ND, IN_ND, bn_in);
    degembed_k<<<NN * ND / 256, 256, 0, stream>>>(h, ind, outd, z_in, z_out);
    mgemm64_k<E_BIAS, 1><<<dim3(2, EE / 64), 256, 0, stream>>>(
        eb, IN_ED, WeT, IN_ED, e_bf, ED, IN_ED, be_in);

    for (int l = 0; l < NL; l++) {
        ln_k<<<NN / 4, 256, 0, stream>>>(h, ln1w + l * ND, ln1b + l * ND, xnb);

        // fused Q/K/V projections: z in {0,1,2} -> qb/kb/vb
        mgemm_k<E_BIAS, 1><<<dim3(16, 16, 3), 256, 0, stream>>>(
            xnb, ND, 0,
            WqT + (size_t)l * H * ND * ND, ND, (long)NL * H * ND * ND,
            qb, H * ND, (long)NN * H * ND,
            ND, bq + l * H * ND, bk + l * H * ND, bv + l * H * ND);
        transp_k<0><<<dim3(32, 32, 1), 256, 0, stream>>>(vb, 0, vT, 0, NN, H * ND);

        dotsT_k<<<dim3(EE / 256, LMAX), 256, 0, stream>>>(
            e_bf, evec + (size_t)l * H * LMAX * ED, dtb);
        bias_k<<<(int)(NN2 / 256), 256, 0, stream>>>(pc0, pc1, pc2, bspat, dtb, sc);

        // split-K fused flash attention + combine
        fattn_k<<<dim3(H, NN / QROWS, SPLIT), 512, 0, stream>>>(qb, kb, vT, sc, ml);
        combine_k<<<H * NN * 32 / 256, 256, 0, stream>>>(sc, ml, o2);

        // h = o2 @ Wo + bo + h
        mgemm64_k<E_BIAS_RES, 0><<<dim3(4, 32), 256, 0, stream>>>(
            o2, H * ND, WoT + (size_t)l * ND * H * ND, H * ND, h, ND, H * ND, bo + l * ND);

        ln_k<<<NN / 4, 256, 0, stream>>>(h, ln2w + l * ND, ln2b + l * ND, xnb);
        mgemm64_k<E_BIAS_GELU, 1><<<dim3(16, 32), 256, 0, stream>>>(
            xnb, ND, W1T + (size_t)l * FF * ND, ND, ff1b, FF, ND, bff1 + l * FF);
        mgemm64_k<E_BIAS_RES, 0><<<dim3(4, 32), 256, 0, stream>>>(
            ff1b, FF, W2T + (size_t)l * ND * FF, FF, h, ND, FF, bff2 + l * ND);
    }

    cvt_k<<<NN * ND / 1024, 256, 0, stream>>>(h, hb);
    mgemm64_k<E_BIAS, 0><<<dim3(4, 32), 256, 0, stream>>>(
        hb, ND, WouT, ND, out, ND, ND, bout);
}

// Round 14
// 743.297 us; speedup vs baseline: 1.6599x; 1.6599x over previous
//
#include <hip/hip_runtime.h>

// ---------------------------------------------------------------------------
// Graphormer forward, MI355X. Round 13 = REVERT to round 11 (741 us proven):
// round 12's single-buffer/SPLIT=8 diet regressed (occupancy flat, write
// amplification 11x). fattn: 1024 thr (16 waves), QROWS=256, SPLIT=4,
// 3-deep K/V LDS buffers + 2-deep LDS-staged bias, vmcnt(2) top wait,
// one barrier pair per tile, shuffle-free softmax (m==0, ones-MFMA).
// ---------------------------------------------------------------------------

constexpr int NN    = 2048;   // nodes
constexpr int EE    = 32768;  // edges
constexpr int IN_ND = 128;
constexpr int ND    = 256;
constexpr int IN_ED = 64;
constexpr int ED    = 128;
constexpr int H     = 8;
constexpr int FF    = 1024;
constexpr int NL    = 3;
constexpr int LMAX  = 5;
constexpr int MAXDEG= 64;
constexpr int SPLIT = 4;
constexpr int KSP   = NN / SPLIT;   // keys per split = 512
constexpr int QROWS = 256;          // q-rows per block

enum { E_NONE = 0, E_BIAS = 1, E_BIAS_RES = 2, E_BIAS_GELU = 3 };

using u16 = unsigned short;
using short8 = __attribute__((ext_vector_type(8))) short;   // 8 bf16 (4 VGPR)
using f32x4  = __attribute__((ext_vector_type(4))) float;
using u32x4  = __attribute__((ext_vector_type(4))) unsigned int;

__device__ __forceinline__ u16 f2bf(float f) {              // RNE f32->bf16
    unsigned u = __float_as_uint(f);
    u += 0x7fff + ((u >> 16) & 1);
    return (u16)(u >> 16);
}
__device__ __forceinline__ float bf2f(u16 h) {
    return __uint_as_float((unsigned)h << 16);
}
__device__ __forceinline__ float gelu_f(float x) {
    return 0.5f * x * (1.0f + erff(x * 0.70710678118654752440f));
}

#define GLL16(gsrc, ldst)                                                     \
    __builtin_amdgcn_global_load_lds(                                         \
        (const __attribute__((address_space(1))) void*)(gsrc),                \
        (__attribute__((address_space(3))) void*)(ldst), 16, 0, 0)

// ---------------------------------------------------------------------------
// bf16 MFMA GEMM, 128x128 tile, BK=32. Used ONLY for fused QKV (grid z=3):
// per-z bias pointer, z-strided A/B/C.
// ---------------------------------------------------------------------------
template<int EPI, int OBF>
__global__ __launch_bounds__(256)
void mgemm_k(const u16* __restrict__ A, int lda, long aZs,
             const u16* __restrict__ B, int ldb, long bZs,
             void* __restrict__ Cp, int ldc, long cZs,
             int K, const float* __restrict__ bias0,
             const float* __restrict__ bias1, const float* __restrict__ bias2)
{
    const int z = blockIdx.z;
    A += (long)z * aZs;
    B += (long)z * bZs;
    const float* bias = (z == 0) ? bias0 : (z == 1 ? bias1 : bias2);
    const int row0 = blockIdx.y * 128, col0 = blockIdx.x * 128;
    const int tid = threadIdx.x;
    const int lane = tid & 63, wv = tid >> 6;
    const int wr = wv >> 1, wc = wv & 1;
    const int fl = lane & 15, kg = lane >> 4;

    __shared__ u16 As[128 * 32];
    __shared__ u16 Bs[128 * 32];

    int aoff[4], boff[4];
#pragma unroll
    for (int m = 0; m < 4; m++) {
        int r = wr * 64 + m * 16 + fl;
        aoff[m] = r * 64 + ((kg ^ ((r >> 1) & 3)) * 16);
        r = wc * 64 + m * 16 + fl;
        boff[m] = r * 64 + ((kg ^ ((r >> 1) & 3)) * 16);
    }

    const int id0 = tid * 2, id1 = id0 + 1;
    const int sr0 = id0 >> 2, sl0 = id0 & 3;
    const int sr1 = id1 >> 2, sl1 = id1 & 3;
    const int wb0 = sr0 * 64 + ((sl0 ^ ((sr0 >> 1) & 3)) * 16);
    const int wb1 = sr1 * 64 + ((sl1 ^ ((sr1 >> 1) & 3)) * 16);
    const u16* ga0 = A + (long)(row0 + sr0) * lda + sl0 * 8;
    const u16* ga1 = A + (long)(row0 + sr1) * lda + sl1 * 8;
    const u16* gb0 = B + (long)(col0 + sr0) * ldb + sl0 * 8;
    const u16* gb1 = B + (long)(col0 + sr1) * ldb + sl1 * 8;

    const f32x4 zero = {0.f, 0.f, 0.f, 0.f};
    f32x4 acc[4][4];
#pragma unroll
    for (int m = 0; m < 4; m++)
#pragma unroll
        for (int n = 0; n < 4; n++) acc[m][n] = zero;

    for (int k0 = 0; k0 < K; k0 += 32) {
        const uint4 va0 = *(const uint4*)(ga0 + k0);
        const uint4 va1 = *(const uint4*)(ga1 + k0);
        const uint4 vb0 = *(const uint4*)(gb0 + k0);
        const uint4 vb1 = *(const uint4*)(gb1 + k0);
        __syncthreads();
        *(uint4*)((char*)As + wb0) = va0;
        *(uint4*)((char*)As + wb1) = va1;
        *(uint4*)((char*)Bs + wb0) = vb0;
        *(uint4*)((char*)Bs + wb1) = vb1;
        __syncthreads();
        short8 af[4], bfr[4];
#pragma unroll
        for (int m = 0; m < 4; m++)
            af[m] = *(const short8*)((const char*)As + aoff[m]);
#pragma unroll
        for (int n = 0; n < 4; n++)
            bfr[n] = *(const short8*)((const char*)Bs + boff[n]);
#pragma unroll
        for (int m = 0; m < 4; m++)
#pragma unroll
            for (int n = 0; n < 4; n++)
                acc[m][n] = __builtin_amdgcn_mfma_f32_16x16x32_bf16(
                    af[m], bfr[n], acc[m][n], 0, 0, 0);
    }

    float* Cf = (float*)Cp + (long)z * cZs;
    u16*   Cb = (u16*)Cp   + (long)z * cZs;
#pragma unroll
    for (int n = 0; n < 4; n++) {
        const int col = col0 + wc * 64 + n * 16 + fl;
        float bcol = 0.f;
        if constexpr (EPI == E_BIAS || EPI == E_BIAS_RES || EPI == E_BIAS_GELU)
            bcol = bias[col];
#pragma unroll
        for (int m = 0; m < 4; m++) {
            const f32x4 v = acc[m][n];
#pragma unroll
            for (int r = 0; r < 4; r++) {
                const int row = row0 + wr * 64 + m * 16 + kg * 4 + r;
                float x = v[r];
                if constexpr (EPI == E_BIAS)       x += bcol;
                else if constexpr (EPI == E_BIAS_RES)  x += bcol + Cf[(long)row * ldc + col];
                else if constexpr (EPI == E_BIAS_GELU) x = gelu_f(x + bcol);
                if constexpr (OBF) Cb[(long)row * ldc + col] = f2bf(x);
                else               Cf[(long)row * ldc + col] = x;
            }
        }
    }
}

// ---------------------------------------------------------------------------
// bf16 MFMA GEMM, 64x64 tile, BK=64.
// ---------------------------------------------------------------------------
template<int EPI, int OBF>
__global__ __launch_bounds__(256)
void mgemm64_k(const u16* __restrict__ A, int lda,
               const u16* __restrict__ B, int ldb,
               void* __restrict__ Cp, int ldc,
               int K, const float* __restrict__ bias)
{
    const int row0 = blockIdx.y * 64, col0 = blockIdx.x * 64;
    const int tid = threadIdx.x, lane = tid & 63, w = tid >> 6;
    const int wr = w >> 1, wc = w & 1;
    const int fl = lane & 15, kg = lane >> 4;

    __shared__ u16 As[64 * 64];
    __shared__ u16 Bs[64 * 64];

    int aoff[2][2], boff[2][2];
#pragma unroll
    for (int m = 0; m < 2; m++)
#pragma unroll
        for (int ks = 0; ks < 2; ks++) {
            int r = wr * 32 + m * 16 + fl;
            aoff[m][ks] = r * 64 + (((ks * 4 + kg) ^ (r & 7)) * 8);
            r = wc * 32 + m * 16 + fl;
            boff[m][ks] = r * 64 + (((ks * 4 + kg) ^ (r & 7)) * 8);
        }
    const int i0 = tid, i1 = tid + 256;
    const int ar0 = i0 >> 3, as0 = i0 & 7, ar1 = i1 >> 3, as1 = i1 & 7;
    const u16* gA0 = A + (long)(row0 + ar0) * lda + ((as0 ^ (ar0 & 7)) * 8);
    const u16* gA1 = A + (long)(row0 + ar1) * lda + ((as1 ^ (ar1 & 7)) * 8);
    const u16* gB0 = B + (long)(col0 + ar0) * ldb + ((as0 ^ (ar0 & 7)) * 8);
    const u16* gB1 = B + (long)(col0 + ar1) * ldb + ((as1 ^ (ar1 & 7)) * 8);

    const f32x4 zero = {0.f, 0.f, 0.f, 0.f};
    f32x4 acc[2][2];
#pragma unroll
    for (int m = 0; m < 2; m++)
#pragma unroll
        for (int n = 0; n < 2; n++) acc[m][n] = zero;

    for (int k0 = 0; k0 < K; k0 += 64) {
        const uint4 a0 = *(const uint4*)(gA0 + k0);
        const uint4 a1 = *(const uint4*)(gA1 + k0);
        const uint4 b0 = *(const uint4*)(gB0 + k0);
        const uint4 b1 = *(const uint4*)(gB1 + k0);
        __syncthreads();
        *(uint4*)((char*)As + i0 * 16) = a0;
        *(uint4*)((char*)As + i1 * 16) = a1;
        *(uint4*)((char*)Bs + i0 * 16) = b0;
        *(uint4*)((char*)Bs + i1 * 16) = b1;
        __syncthreads();
        short8 af[2][2], bf_[2][2];
#pragma unroll
        for (int m = 0; m < 2; m++)
#pragma unroll
            for (int ks = 0; ks < 2; ks++) {
                af[m][ks]  = *(const short8*)(As + aoff[m][ks]);
                bf_[m][ks] = *(const short8*)(Bs + boff[m][ks]);
            }
#pragma unroll
        for (int m = 0; m < 2; m++)
#pragma unroll
            for (int n = 0; n < 2; n++)
#pragma unroll
                for (int ks = 0; ks < 2; ks++)
                    acc[m][n] = __builtin_amdgcn_mfma_f32_16x16x32_bf16(
                        af[m][ks], bf_[n][ks], acc[m][n], 0, 0, 0);
    }

    float* Cf = (float*)Cp;
    u16*   Cb = (u16*)Cp;
#pragma unroll
    for (int n = 0; n < 2; n++) {
        const int col = col0 + wc * 32 + n * 16 + fl;
        float bcol = 0.f;
        if constexpr (EPI == E_BIAS || EPI == E_BIAS_RES || EPI == E_BIAS_GELU)
            bcol = bias[col];
#pragma unroll
        for (int m = 0; m < 2; m++) {
            const f32x4 v = acc[m][n];
#pragma unroll
            for (int r = 0; r < 4; r++) {
                const int row = row0 + wr * 32 + m * 16 + kg * 4 + r;
                float x = v[r];
                if constexpr (EPI == E_BIAS)       x += bcol;
                else if constexpr (EPI == E_BIAS_RES)  x += bcol + Cf[(long)row * ldc + col];
                else if constexpr (EPI == E_BIAS_GELU) x = gelu_f(x + bcol);
                if constexpr (OBF) Cb[(long)row * ldc + col] = f2bf(x);
                else               Cf[(long)row * ldc + col] = x;
            }
        }
    }
}

// ---------------------------------------------------------------------------
// Async split-K flash attention, ONE barrier pair per tile, shuffle-free
// softmax, LDS-staged bias. Grid (H, NN/256, SPLIT) = 256 blocks, 16 waves.
// Per-tile vmem ops (uniform): [bias(t+1) 1][stage(t+2) 2]. Top-of-tile queue
// oldest->newest: bias(t-1), stage(t)(2), bias(t), stage(t+1)(2) -> vmcnt(2)
// proves stage(t)+bias(t) landed. Bias LDS per-wave private, 2 buffers.
// ---------------------------------------------------------------------------
__global__ __launch_bounds__(1024, 4)
void fattn_k(const u16* __restrict__ qb, const u16* __restrict__ kb,
             const u16* __restrict__ vT, u16* __restrict__ sc,
             float* __restrict__ ml)
{
    const int hh = blockIdx.x;
    const int row0 = blockIdx.y * QROWS;
    const int sp = blockIdx.z;
    const int kbase = sp * KSP;
    constexpr int NT = KSP / 32;       // 16 tiles
    const int tid = threadIdx.x, lane = tid & 63, w = tid >> 6;   // w 0..15
    const int fl = lane & 15, kg = lane >> 4;
    const long NN2 = (long)NN * NN;

    __shared__ u16 Ks[3 * 32 * 256];   // 3 x 16KB [buf][keyrow][256k] swz
    __shared__ u16 Vs[3 * 256 * 32];   // 3 x 16KB [buf][d][32keys] swz
    __shared__ u16 Bls[2 * 256 * 32];  // 2 x 16KB bias [buf][row][32cols]
    __shared__ u16 Ps[16 * 16 * 40];   // per-wave P tile, pitch 40

    auto stage = [&](int t, int buf) {
        const int kt0 = kbase + t * 32;
        const int kr = tid >> 5, ksl = tid & 31;
        GLL16(kb + (long)(kt0 + kr) * (H * ND) + hh * ND + ((ksl ^ (kr & 7)) * 8),
              Ks + buf * 8192 + tid * 8);
        const int vr = tid >> 2, vsl = tid & 3;
        GLL16(vT + (long)(hh * ND + vr) * NN + kt0 + ((vsl ^ ((vr >> 1) & 3)) * 8),
              Vs + buf * 8192 + tid * 8);
    };
    auto stage_bias = [&](int t, int buf) {
        const u16* g = sc + (long)hh * NN2 + (long)(row0 + (tid >> 2)) * NN
                     + kbase + t * 32 + (tid & 3) * 8;
        GLL16(g, Bls + buf * 8192 + tid * 8);
    };

    // Q fragments FIRST (oldest in vmem queue; retired by first vmcnt(2))
    short8 qf[8];
    {
        const u16* qrow = qb + (long)(row0 + w * 16 + fl) * (H * ND) + hh * ND;
#pragma unroll
        for (int ks = 0; ks < 8; ks++)
            qf[ks] = *(const short8*)(qrow + ks * 32 + kg * 8);
    }
    stage_bias(0, 0);
    stage(0, 0);
    stage(1, 1);

    short8 ones;                        // bf16 1.0 x8 (0x3F80)
#pragma unroll
    for (int i = 0; i < 8; i++) ones[i] = (short)0x3F80;

    f32x4 O[16];
#pragma unroll
    for (int of = 0; of < 16; of++) O[of] = f32x4{0.f, 0.f, 0.f, 0.f};
    f32x4 lac = {0.f, 0.f, 0.f, 0.f};   // row-sums via ones-MFMA

    const float scale = 1.f / 16.f;
    for (int t = 0; t < NT; t++) {
        asm volatile("s_waitcnt vmcnt(2)" ::: "memory");  // stage(t)+bias(t) landed
        __builtin_amdgcn_sched_barrier(0);
        asm volatile("s_barrier" ::: "memory");            // all waves done t-1
        __builtin_amdgcn_sched_barrier(0);

        stage_bias((t + 1) % NT, (t + 1) & 1);  // per-wave private buf
        stage((t + 2) % NT, (t + 2) % 3);       // overwrite buf[(t-1)%3]: safe

        const int cb = t % 3;
        // S = Q K^T from Ks[cb]
        f32x4 s[2] = {f32x4{0.f,0.f,0.f,0.f}, f32x4{0.f,0.f,0.f,0.f}};
        __builtin_amdgcn_s_setprio(1);
#pragma unroll
        for (int ks = 0; ks < 8; ks++)
#pragma unroll
            for (int cf = 0; cf < 2; cf++) {
                const int mlr = cf * 16 + fl;
                const short8 kf = *(const short8*)(Ks + cb * 8192 + mlr * 256
                                                   + (((ks * 4 + kg) ^ (mlr & 7)) * 8));
                s[cf] = __builtin_amdgcn_mfma_f32_16x16x32_bf16(qf[ks], kf, s[cf], 0, 0, 0);
            }
        __builtin_amdgcn_s_setprio(0);

        // P = exp(s*scale + bias), bias fragment from LDS (lgkm-ordered)
        const u16* bl = Bls + (t & 1) * 8192 + (w * 16 + kg * 4) * 32;
        float p[2][4];
#pragma unroll
        for (int cf = 0; cf < 2; cf++)
#pragma unroll
            for (int r = 0; r < 4; r++)
                p[cf][r] = __expf(s[cf][r] * scale
                                  + bf2f(bl[r * 32 + cf * 16 + fl]));
        // P -> per-wave LDS bounce (no cross-wave sharing -> no barrier)
#pragma unroll
        for (int cf = 0; cf < 2; cf++)
#pragma unroll
            for (int r = 0; r < 4; r++)
                Ps[w * 640 + (kg * 4 + r) * 40 + cf * 16 + fl] = f2bf(p[cf][r]);

        // PV: O += P * V  from Vs[cb]; l += P * 1 (ones-MFMA)
        const short8 pa = *(const short8*)(Ps + w * 640 + fl * 40 + kg * 8);
        __builtin_amdgcn_s_setprio(1);
        lac = __builtin_amdgcn_mfma_f32_16x16x32_bf16(pa, ones, lac, 0, 0, 0);
#pragma unroll
        for (int of = 0; of < 16; of++) {
            const int d = of * 16 + fl;
            const short8 vf = *(const short8*)(Vs + cb * 8192 + d * 32
                                               + ((kg ^ ((d >> 1) & 3)) * 8));
            O[of] = __builtin_amdgcn_mfma_f32_16x16x32_bf16(pa, vf, O[of], 0, 0, 0);
        }
        __builtin_amdgcn_s_setprio(0);

        asm volatile("s_waitcnt lgkmcnt(0)" ::: "memory");
        __builtin_amdgcn_sched_barrier(0);
        asm volatile("s_barrier" ::: "memory");            // all reads of buf[cb] done
        __builtin_amdgcn_sched_barrier(0);
    }

    // ---- epilogue: UNNORMALIZED O -> sc cols [sp*512, sp*512+256), l -> ml
    u16* op = sc + (long)hh * NN2 + sp * KSP;
#pragma unroll
    for (int of = 0; of < 16; of++)
#pragma unroll
        for (int r = 0; r < 4; r++) {
            const int row = row0 + w * 16 + kg * 4 + r;
            op[(long)row * NN + of * 16 + fl] = f2bf(O[of][r]);
        }
    if (fl == 0) {
#pragma unroll
        for (int r = 0; r < 4; r++) {
            const int row = row0 + w * 16 + kg * 4 + r;
            ml[((long)sp * H + hh) * NN + row] = lac[r];
        }
    }
}

// ---------------------------------------------------------------------------
// Combine split partials: o2[n][h*256+d] = sum_z O_z / sum_z l_z (unweighted).
// ---------------------------------------------------------------------------
__global__ __launch_bounds__(256)
void combine_k(const u16* __restrict__ sc, const float* __restrict__ ml,
               u16* __restrict__ o2)
{
    const int idx = blockIdx.x * 256 + threadIdx.x;
    const int d8 = idx & 31;
    const int n  = (idx >> 5) & (NN - 1);
    const int h  = idx >> 16;
    const long NN2 = (long)NN * NN;
    float L = 0.f;
#pragma unroll
    for (int z = 0; z < SPLIT; z++)
        L += ml[((long)z * H + h) * NN + n];
    const float invL = 1.f / L;
    float acc[8] = {0.f,0.f,0.f,0.f,0.f,0.f,0.f,0.f};
#pragma unroll
    for (int z = 0; z < SPLIT; z++) {
        const u32x4 q = *(const u32x4*)(sc + (long)h * NN2 + (long)n * NN
                                        + z * KSP + d8 * 8);
        acc[0] += bf2f(q.x & 0xffff); acc[1] += bf2f(q.x >> 16);
        acc[2] += bf2f(q.y & 0xffff); acc[3] += bf2f(q.y >> 16);
        acc[4] += bf2f(q.z & 0xffff); acc[5] += bf2f(q.z >> 16);
        acc[6] += bf2f(q.w & 0xffff); acc[7] += bf2f(q.w >> 16);
    }
    uint4 o;
    o.x = (unsigned)f2bf(acc[0] * invL) | ((unsigned)f2bf(acc[1] * invL) << 16);
    o.y = (unsigned)f2bf(acc[2] * invL) | ((unsigned)f2bf(acc[3] * invL) << 16);
    o.z = (unsigned)f2bf(acc[4] * invL) | ((unsigned)f2bf(acc[5] * invL) << 16);
    o.w = (unsigned)f2bf(acc[6] * invL) | ((unsigned)f2bf(acc[7] * invL) << 16);
    *(uint4*)(o2 + (long)n * (H * ND) + h * ND + d8 * 8) = o;
}

// ---------------------------------------------------------------------------
// Tiled transpose + (optional) f32->bf16 convert.
// ---------------------------------------------------------------------------
template<int INF32>
__global__ __launch_bounds__(256)
void transp_k(const void* __restrict__ inp, long inZs,
              u16* __restrict__ out, long outZs, int R, int C)
{
    const int z = blockIdx.z;
    const int r0 = blockIdx.y * 64, c0 = blockIdx.x * 64;
    __shared__ u16 t[64][68];
    const int tx = threadIdx.x & 63, ty = threadIdx.x >> 6;
    if constexpr (INF32) {
        const float* in = (const float*)inp + (long)z * inZs;
#pragma unroll
        for (int i = 0; i < 16; i++) {
            const int r = i * 4 + ty;
            t[r][tx] = f2bf(in[(long)(r0 + r) * C + c0 + tx]);
        }
    } else {
        const u16* in = (const u16*)inp + (long)z * inZs;
#pragma unroll
        for (int i = 0; i < 16; i++) {
            const int r = i * 4 + ty;
            t[r][tx] = in[(long)(r0 + r) * C + c0 + tx];
        }
    }
    __syncthreads();
    u16* o = out + (long)z * outZs;
#pragma unroll
    for (int i = 0; i < 16; i++) {
        const int r = i * 4 + ty;
        o[(long)(c0 + r) * R + r0 + tx] = t[tx][r];
    }
}

// elementwise f32 -> bf16
__global__ __launch_bounds__(256)
void cvt_k(const float* __restrict__ in, u16* __restrict__ out)
{
    const long i = (long)blockIdx.x * 256 + threadIdx.x;
    const float4 v = ((const float4*)in)[i];
    ushort4 o;
    o.x = f2bf(v.x); o.y = f2bf(v.y); o.z = f2bf(v.z); o.w = f2bf(v.w);
    ((ushort4*)out)[i] = o;
}

// ---------------------------------------------------------------------------
// LayerNorm rows of ND=256, f32 in -> bf16 out.
// ---------------------------------------------------------------------------
__global__ __launch_bounds__(256)
void ln_k(const float* __restrict__ x, const float* __restrict__ w,
          const float* __restrict__ b, u16* __restrict__ y)
{
    const int wid = threadIdx.x >> 6, lane = threadIdx.x & 63;
    const int row = blockIdx.x * 4 + wid;
    const float4 v = reinterpret_cast<const float4*>(x + (long)row * ND)[lane];
    float s = v.x + v.y + v.z + v.w;
#pragma unroll
    for (int o = 32; o >= 1; o >>= 1) s += __shfl_xor(s, o);
    const float mean = s * (1.f / ND);
    const float d0 = v.x - mean, d1 = v.y - mean, d2 = v.z - mean, d3 = v.w - mean;
    float sq = d0 * d0 + d1 * d1 + d2 * d2 + d3 * d3;
#pragma unroll
    for (int o = 32; o >= 1; o >>= 1) sq += __shfl_xor(sq, o);
    const float rstd = rsqrtf(sq * (1.f / ND) + 1e-5f);
    const float4 wv = reinterpret_cast<const float4*>(w)[lane];
    const float4 bv = reinterpret_cast<const float4*>(b)[lane];
    ushort4 o4;
    o4.x = f2bf(d0 * rstd * wv.x + bv.x);
    o4.y = f2bf(d1 * rstd * wv.y + bv.y);
    o4.z = f2bf(d2 * rstd * wv.z + bv.z);
    o4.w = f2bf(d3 * rstd * wv.w + bv.w);
    reinterpret_cast<ushort4*>(y + (long)row * ND)[lane] = o4;
}

// ---------------------------------------------------------------------------
// Edge-dot precompute, bf16 out: dtb[s][e][h]. grid (EE/256, LMAX)
// ---------------------------------------------------------------------------
__global__ __launch_bounds__(256)
void dotsT_k(const u16* __restrict__ e, const float* __restrict__ evl,
             u16* __restrict__ dtb)
{
    const int s = blockIdx.y;
    const int ei = blockIdx.x * 256 + threadIdx.x;
    __shared__ float evs[H * ED];
    for (int i = threadIdx.x; i < H * ED; i += 256)
        evs[i] = evl[((i >> 7) * LMAX + s) * ED + (i & 127)];
    __syncthreads();
    const uint4* er = (const uint4*)(e + (long)ei * ED);
    float c[H];
#pragma unroll
    for (int h = 0; h < H; h++) c[h] = 0.f;
#pragma unroll
    for (int d8 = 0; d8 < ED / 8; d8++) {
        const uint4 q = er[d8];
        float f[8];
        f[0] = bf2f(q.x & 0xffff); f[1] = bf2f(q.x >> 16);
        f[2] = bf2f(q.y & 0xffff); f[3] = bf2f(q.y >> 16);
        f[4] = bf2f(q.z & 0xffff); f[5] = bf2f(q.z >> 16);
        f[6] = bf2f(q.w & 0xffff); f[7] = bf2f(q.w >> 16);
#pragma unroll
        for (int h = 0; h < H; h++) {
            const float* w = &evs[h * ED + d8 * 8];
            c[h] += w[0] * f[0] + w[1] * f[1] + w[2] * f[2] + w[3] * f[3]
                  + w[4] * f[4] + w[5] * f[5] + w[6] * f[6] + w[7] * f[7];
        }
    }
    uint4 o;
    o.x = (unsigned)f2bf(c[0]) | ((unsigned)f2bf(c[1]) << 16);
    o.y = (unsigned)f2bf(c[2]) | ((unsigned)f2bf(c[3]) << 16);
    o.z = (unsigned)f2bf(c[4]) | ((unsigned)f2bf(c[5]) << 16);
    o.w = (unsigned)f2bf(c[6]) | ((unsigned)f2bf(c[7]) << 16);
    *(uint4*)(dtb + ((long)s * EE + ei) * H) = o;
}

// ---------------------------------------------------------------------------
// Path compaction.
// ---------------------------------------------------------------------------
__global__ __launch_bounds__(256)
void pack_k(const int* __restrict__ ndist, const int* __restrict__ epaths,
            unsigned* __restrict__ pc0, unsigned* __restrict__ pc1,
            unsigned* __restrict__ pc2)
{
    const long idx = (long)blockIdx.x * 256 + threadIdx.x;
    const unsigned d = (unsigned)ndist[idx];
    const int* ep = epaths + idx * LMAX;
    const unsigned e0 = ep[0], e1 = ep[1], e2 = ep[2], e3 = ep[3], e4 = ep[4];
    pc0[idx] = d | (e0 << 8);
    pc1[idx] = e1 | (e2 << 16);
    pc2[idx] = e3 | (e4 << 16);
}

// ---------------------------------------------------------------------------
// Attention bias -> bf16 scores init.
// ---------------------------------------------------------------------------
__global__ __launch_bounds__(256)
void bias_k(const unsigned* __restrict__ pc0, const unsigned* __restrict__ pc1,
            const unsigned* __restrict__ pc2, const float* __restrict__ bspat,
            const u16* __restrict__ dtb, u16* __restrict__ sc)
{
    const long idx = (long)blockIdx.x * 256 + threadIdx.x;
    const unsigned w0 = pc0[idx], w1 = pc1[idx], w2 = pc2[idx];
    const int d = (int)(w0 & 255u);
    float bb = 0.f;
    if (d > 0) bb = bspat[(d < LMAX ? d : LMAX) - 1];
    int npe = d - 1;
    npe = npe < 0 ? 0 : (npe > LMAX ? LMAX : npe);
    const int ep[LMAX] = { (int)(w0 >> 8), (int)(w1 & 0xffffu), (int)(w1 >> 16),
                           (int)(w2 & 0xffffu), (int)(w2 >> 16) };
    float c[H];
#pragma unroll
    for (int h = 0; h < H; h++) c[h] = 0.f;
#pragma unroll
    for (int s = 0; s < LMAX; s++) {
        if (s < npe) {
            const uint4 q = *(const uint4*)(dtb + ((long)s * EE + ep[s]) * H);
            c[0] += bf2f(q.x & 0xffff); c[1] += bf2f(q.x >> 16);
            c[2] += bf2f(q.y & 0xffff); c[3] += bf2f(q.y >> 16);
            c[4] += bf2f(q.z & 0xffff); c[5] += bf2f(q.z >> 16);
            c[6] += bf2f(q.w & 0xffff); c[7] += bf2f(q.w >> 16);
        }
    }
    const float inv = npe > 0 ? 1.f / (float)npe : 0.f;
    const long NN2 = (long)NN * NN;
#pragma unroll
    for (int h = 0; h < H; h++)
        sc[(long)h * NN2 + idx] = f2bf(bb + c[h] * inv);
}

__global__ void deg_k(const int* __restrict__ ei, int* __restrict__ ind,
                      int* __restrict__ outd)
{
    const int e = blockIdx.x * 256 + threadIdx.x;
    atomicAdd(&outd[ei[e]], 1);
    atomicAdd(&ind[ei[EE + e]], 1);
}

__global__ void degembed_k(float* __restrict__ h, const int* __restrict__ ind,
                           const int* __restrict__ outd,
                           const float* __restrict__ z_in,
                           const float* __restrict__ z_out)
{
    const int idx = blockIdx.x * 256 + threadIdx.x;
    const int n = idx >> 8, c = idx & 255;
    int di = ind[n];  di = di > (MAXDEG - 1) ? (MAXDEG - 1) : di;
    int dw = outd[n]; dw = dw > (MAXDEG - 1) ? (MAXDEG - 1) : dw;
    h[idx] += z_in[di * ND + c] + z_out[dw * ND + c];
}

__global__ void sentinel_k(float* o) { o[0] = 12345.0f; }

// ---------------------------------------------------------------------------
extern "C" void kernel_launch(void* const* d_in, const int* in_sizes, int n_in,
                              void* d_out, int out_size, void* d_ws, size_t ws_size,
                              hipStream_t stream)
{
    const float* x      = (const float*)d_in[0];
    const int*   eidx   = (const int*)d_in[1];
    const float* eattr  = (const float*)d_in[2];
    const int*   ndist  = (const int*)d_in[3];
    const int*   epaths = (const int*)d_in[4];
    const float* Wn_in  = (const float*)d_in[5];
    const float* bn_in  = (const float*)d_in[6];
    const float* We_in  = (const float*)d_in[7];
    const float* be_in  = (const float*)d_in[8];
    const float* z_in   = (const float*)d_in[9];
    const float* z_out  = (const float*)d_in[10];
    const float* bspat  = (const float*)d_in[11];
    const float* ln1w   = (const float*)d_in[12];
    const float* ln1b   = (const float*)d_in[13];
    const float* ln2w   = (const float*)d_in[14];
    const float* ln2b   = (const float*)d_in[15];
    const float* Wq     = (const float*)d_in[16];
    const float* bq     = (const float*)d_in[17];
    const float* Wk     = (const float*)d_in[18];
    const float* bk     = (const float*)d_in[19];
    const float* Wv     = (const float*)d_in[20];
    const float* bv     = (const float*)d_in[21];
    const float* evec   = (const float*)d_in[22];
    const float* Wo     = (const float*)d_in[23];
    const float* bo     = (const float*)d_in[24];
    const float* Wff1   = (const float*)d_in[25];
    const float* bff1   = (const float*)d_in[26];
    const float* Wff2   = (const float*)d_in[27];
    const float* bff2   = (const float*)d_in[28];
    const float* Wout   = (const float*)d_in[29];
    const float* bout   = (const float*)d_in[30];
    float* out = (float*)d_out;

    // ---- workspace carve-up ----
    char* p = (char*)d_ws;
    auto alloc = [&](size_t bytes) -> char* {
        char* r = p;
        p += (bytes + 255) & ~(size_t)255;
        return r;
    };
    float* h    = (float*)alloc((size_t)NN * ND * 4);
    u16*   hb   = (u16*)alloc((size_t)NN * ND * 2);
    u16*   xb   = (u16*)alloc((size_t)NN * IN_ND * 2);
    u16*   xnb  = (u16*)alloc((size_t)NN * ND * 2);
    u16*   eb   = (u16*)alloc((size_t)EE * IN_ED * 2);
    u16*   e_bf = (u16*)alloc((size_t)EE * ED * 2);
    u16*   qb   = (u16*)alloc((size_t)NN * H * ND * 2);   // qb,kb,vb contiguous
    u16*   kb   = (u16*)alloc((size_t)NN * H * ND * 2);
    u16*   vb   = (u16*)alloc((size_t)NN * H * ND * 2);
    u16*   vT   = (u16*)alloc((size_t)NN * H * ND * 2);
    u16*   o2   = (u16*)alloc((size_t)NN * H * ND * 2);
    u16*   ff1b = (u16*)alloc((size_t)NN * FF * 2);
    u16*   dtb  = (u16*)alloc((size_t)LMAX * EE * H * 2);
    u16*   WqT  = (u16*)alloc((size_t)NL * H * ND * ND * 2);  // WqT,WkT,WvT contiguous
    u16*   WkT  = (u16*)alloc((size_t)NL * H * ND * ND * 2);
    u16*   WvT  = (u16*)alloc((size_t)NL * H * ND * ND * 2);
    u16*   WoT  = (u16*)alloc((size_t)NL * ND * H * ND * 2);
    u16*   W1T  = (u16*)alloc((size_t)NL * FF * ND * 2);
    u16*   W2T  = (u16*)alloc((size_t)NL * ND * FF * 2);
    u16*   WnT  = (u16*)alloc((size_t)ND * IN_ND * 2);
    u16*   WeT  = (u16*)alloc((size_t)ED * IN_ED * 2);
    u16*   WouT = (u16*)alloc((size_t)ND * ND * 2);
    int*   ind  = (int*)alloc(NN * 4);
    int*   outd = (int*)alloc(NN * 4);
    unsigned* pc0 = (unsigned*)alloc((size_t)NN * NN * 4);
    unsigned* pc1 = (unsigned*)alloc((size_t)NN * NN * 4);
    unsigned* pc2 = (unsigned*)alloc((size_t)NN * NN * 4);
    float* ml   = (float*)alloc((size_t)SPLIT * H * NN * 4);
    u16*   sc   = (u16*)alloc((size_t)H * NN * NN * 2);
    if ((size_t)(p - (char*)d_ws) > ws_size) {
        sentinel_k<<<1, 1, 0, stream>>>(out);
        return;
    }

    const long NN2 = (long)NN * NN;

    // ---- degrees + path compaction ----
    hipMemsetAsync(ind, 0, NN * 4, stream);
    hipMemsetAsync(outd, 0, NN * 4, stream);
    deg_k<<<EE / 256, 256, 0, stream>>>(eidx, ind, outd);
    pack_k<<<(int)(NN2 / 256), 256, 0, stream>>>(ndist, epaths, pc0, pc1, pc2);

    // ---- input converts + weight transposes ----
    cvt_k<<<NN * IN_ND / 1024, 256, 0, stream>>>(x, xb);
    cvt_k<<<EE * IN_ED / 1024, 256, 0, stream>>>(eattr, eb);
    transp_k<1><<<dim3(4, 4, NL * H), 256, 0, stream>>>(Wq, ND * ND, WqT, ND * ND, ND, ND);
    transp_k<1><<<dim3(4, 4, NL * H), 256, 0, stream>>>(Wk, ND * ND, WkT, ND * ND, ND, ND);
    transp_k<1><<<dim3(4, 4, NL * H), 256, 0, stream>>>(Wv, ND * ND, WvT, ND * ND, ND, ND);
    transp_k<1><<<dim3(4, 32, NL), 256, 0, stream>>>(Wo, (long)H * ND * ND, WoT, (long)H * ND * ND, H * ND, ND);
    transp_k<1><<<dim3(16, 4, NL), 256, 0, stream>>>(Wff1, (long)ND * FF, W1T, (long)ND * FF, ND, FF);
    transp_k<1><<<dim3(4, 16, NL), 256, 0, stream>>>(Wff2, (long)ND * FF, W2T, (long)ND * FF, FF, ND);
    transp_k<1><<<dim3(4, 2, 1), 256, 0, stream>>>(Wn_in, 0, WnT, 0, IN_ND, ND);
    transp_k<1><<<dim3(2, 1, 1), 256, 0, stream>>>(We_in, 0, WeT, 0, IN_ED, ED);
    transp_k<1><<<dim3(4, 4, 1), 256, 0, stream>>>(Wout, 0, WouT, 0, ND, ND);

    // ---- input projections ----
    mgemm64_k<E_BIAS, 0><<<dim3(4, 32), 256, 0, stream>>>(
        xb, IN_ND, WnT, IN_ND, h, ND, IN_ND, bn_in);
    degembed_k<<<NN * ND / 256, 256, 0, stream>>>(h, ind, outd, z_in, z_out);
    mgemm64_k<E_BIAS, 1><<<dim3(2, EE / 64), 256, 0, stream>>>(
        eb, IN_ED, WeT, IN_ED, e_bf, ED, IN_ED, be_in);

    for (int l = 0; l < NL; l++) {
        ln_k<<<NN / 4, 256, 0, stream>>>(h, ln1w + l * ND, ln1b + l * ND, xnb);

        // fused Q/K/V projections: z in {0,1,2} -> qb/kb/vb
        mgemm_k<E_BIAS, 1><<<dim3(16, 16, 3), 256, 0, stream>>>(
            xnb, ND, 0,
            WqT + (size_t)l * H * ND * ND, ND, (long)NL * H * ND * ND,
            qb, H * ND, (long)NN * H * ND,
            ND, bq + l * H * ND, bk + l * H * ND, bv + l * H * ND);
        transp_k<0><<<dim3(32, 32, 1), 256, 0, stream>>>(vb, 0, vT, 0, NN, H * ND);

        dotsT_k<<<dim3(EE / 256, LMAX), 256, 0, stream>>>(
            e_bf, evec + (size_t)l * H * LMAX * ED, dtb);
        bias_k<<<(int)(NN2 / 256), 256, 0, stream>>>(pc0, pc1, pc2, bspat, dtb, sc);

        // async split-K fused flash attention + combine
        fattn_k<<<dim3(H, NN / QROWS, SPLIT), 1024, 0, stream>>>(qb, kb, vT, sc, ml);
        combine_k<<<H * NN * 32 / 256, 256, 0, stream>>>(sc, ml, o2);

        // h = o2 @ Wo + bo + h
        mgemm64_k<E_BIAS_RES, 0><<<dim3(4, 32), 256, 0, stream>>>(
            o2, H * ND, WoT + (size_t)l * ND * H * ND, H * ND, h, ND, H * ND, bo + l * ND);

        ln_k<<<NN / 4, 256, 0, stream>>>(h, ln2w + l * ND, ln2b + l * ND, xnb);
        mgemm64_k<E_BIAS_GELU, 1><<<dim3(16, 32), 256, 0, stream>>>(
            xnb, ND, W1T + (size_t)l * FF * ND, ND, ff1b, FF, ND, bff1 + l * FF);
        mgemm64_k<E_BIAS_RES, 0><<<dim3(4, 32), 256, 0, stream>>>(
            ff1b, FF, W2T + (size_t)l * ND * FF, FF, h, ND, FF, bff2 + l * ND);
    }

    cvt_k<<<NN * ND / 1024, 256, 0, stream>>>(h, hb);
    mgemm64_k<E_BIAS, 0><<<dim3(4, 32), 256, 0, stream>>>(
        hb, ND, WouT, ND, out, ND, ND, bout);
}